// Round 8
// baseline (93.194 us; speedup 1.0000x reference)
//
#include <hip/hip_runtime.h>

// Problem: N=2048, M=512, D=128, all fp32.
// Outputs (flat): [0]=min_loss, [1]=wise_min_loss, [2..2+N*D)=z_out.
//
// R8: compiler-generated packed fp32 (v_pk_*_f32) via ext_vector float2 —
// R7's inline asm pinned the scheduler; native vector ops let clang pick
// v_pk_add/mul/min/fma AND software-pipeline the loads.
//  - elem: lane owns a d-pair; 1 coalesced dwordx2 z-load per n;
//    pk_sub+pk_mul+pk_min = 1.5 inst/elem (scalar was 3).
//  - sum:  v2f sub+fma = 1 inst/elem (scalar was 2).
// Dispatch 1 (k_part, 640 blocks): [0,128)=elem, [128,384)=sum, [384,640)=mask.
//   mask block 0 zeroes acc/counter for dispatch 2.
// Dispatch 2 (k_fin, 64 blocks): reduce partials -> means -> out[0..1].
//
// ws layout (floats):
//   [0 .. 524288)        pb_elem[chunk][m][d]   (8*512*128, 2MB)
//   [524288 .. 540672)   pb_sum[m][32]          (512*32)
//   [540672 .. +2)       acc[2]
//   [540674]             counter (uint)

#define N_ 2048
#define M_ 512
#define D_ 128
#define PB_SUM  (8 * M_ * D_)          // 524288
#define ACC_OFF (PB_SUM + M_ * 32)     // 540672
#define CNT_OFF (ACC_OFF + 2)

typedef float v2f __attribute__((ext_vector_type(2)));

__global__ void __launch_bounds__(256, 3) k_part(
        const float* __restrict__ z, const float* __restrict__ e,
        const float* __restrict__ probs, const float* __restrict__ drop,
        float* __restrict__ out, float* __restrict__ ws) {
    const int bx = blockIdx.x;
    const int t  = threadIdx.x;

    if (bx < 128) {
        // ---- elem partials: min over one 256-n chunk for 32 m's ----
        // lane owns d-pair dp (d = 2*dp, 2*dp+1); t>>6 selects m-octet.
        const int mg = bx >> 3, chunk = bx & 7;
        const int dp = t & 63;
        const int sub = t >> 6;
        const int m0 = mg * 32 + sub * 8;
        const int n0 = chunk * 256;

        v2f ev[8], mn[8];
        const v2f inf2 = { __uint_as_float(0x7f800000u),
                           __uint_as_float(0x7f800000u) };
        #pragma unroll
        for (int k = 0; k < 8; ++k) {
            ev[k] = *reinterpret_cast<const v2f*>(e + (m0 + k) * D_ + 2 * dp);
            mn[k] = inf2;
        }
        const v2f* zp = reinterpret_cast<const v2f*>(z + n0 * D_) + dp;
        #pragma unroll 4
        for (int i = 0; i < 256; ++i) {
            v2f zz = zp[i * 64];                // one dwordx2, 512B/wave
            #pragma unroll
            for (int k = 0; k < 8; ++k) {
                v2f dd = zz - ev[k];            // v_pk_add (neg)
                v2f sq = dd * dd;               // v_pk_mul
                mn[k] = __builtin_elementwise_min(mn[k], sq);  // v_pk_min
            }
        }
        float* pe = ws + (size_t)chunk * (M_ * D_) + m0 * D_ + 2 * dp;
        #pragma unroll
        for (int k = 0; k < 8; ++k)
            *reinterpret_cast<v2f*>(pe + k * D_) = mn[k];
    } else if (bx < 384) {
        // ---- sum partials: thread owns n; d in 4 chunks of 8 float4 ----
        const int b = bx - 128;
        const int nb = b >> 5, mt = b & 31;
        const int n = nb * 256 + t;
        const int m0 = mt * 16;

        v2f acc[16];
        #pragma unroll
        for (int k = 0; k < 16; ++k) acc[k] = (v2f)0.f;

        const float4* z4 = reinterpret_cast<const float4*>(z) + n * 32;
        const float4* e4 = reinterpret_cast<const float4*>(e);

        #pragma unroll 1
        for (int dc = 0; dc < 4; ++dc) {
            float4 zq[8];
            #pragma unroll
            for (int jj = 0; jj < 8; ++jj) zq[jj] = z4[dc * 8 + jj];
            #pragma unroll
            for (int k = 0; k < 16; ++k) {
                const float4* ep = e4 + (m0 + k) * 32 + dc * 8;
                v2f ca = (v2f)0.f, cb = (v2f)0.f;   // two chains
                #pragma unroll
                for (int jj = 0; jj < 8; ++jj) {
                    float4 evq = ep[jj];            // wave-uniform broadcast
                    v2f zlo = { zq[jj].x, zq[jj].y };
                    v2f zhi = { zq[jj].z, zq[jj].w };
                    v2f elo = { evq.x, evq.y };
                    v2f ehi = { evq.z, evq.w };
                    v2f d0 = zlo - elo;             // v_pk_add (neg)
                    ca += d0 * d0;                  // v_pk_fma (contract)
                    v2f d1 = zhi - ehi;
                    cb += d1 * d1;
                }
                acc[k] += ca + cb;
            }
        }
        float s[16];
        #pragma unroll
        for (int k = 0; k < 16; ++k) s[k] = acc[k].x + acc[k].y;
        #pragma unroll
        for (int off = 32; off; off >>= 1) {
            #pragma unroll
            for (int k = 0; k < 16; ++k)
                s[k] = fminf(s[k], __shfl_xor(s[k], off));
        }
        if ((t & 63) == 0) {
            const int w = t >> 6;
            #pragma unroll
            for (int k = 0; k < 16; ++k)
                ws[PB_SUM + (m0 + k) * 32 + nb * 4 + w] = s[k];
        }
    } else {
        // ---- dropout mask; block 384 zeroes acc/counter for k_fin ----
        const int b = bx - 384;
        const int i = b * 256 + t;              // float4 index, 65536 total
        const int n = i >> 5;
        const float p = probs[n];
        const float4 zv = reinterpret_cast<const float4*>(z)[i];
        const float4 dv = reinterpret_cast<const float4*>(drop)[i];
        float2 lo, hi;
        lo.x = dv.x < p ? zv.x : 0.f;
        lo.y = dv.y < p ? zv.y : 0.f;
        hi.x = dv.z < p ? zv.z : 0.f;
        hi.y = dv.w < p ? zv.w : 0.f;
        float2* o = reinterpret_cast<float2*>(out + 2) + i * 2;
        o[0] = lo;
        o[1] = hi;
        if (b == 0 && t == 0) {
            ws[ACC_OFF] = 0.f;
            ws[ACC_OFF + 1] = 0.f;
            reinterpret_cast<unsigned int*>(ws)[CNT_OFF] = 0u;
        }
    }
}

__device__ __forceinline__ float min4(float4 v) {
    return fminf(fminf(v.x, v.y), fminf(v.z, v.w));
}

__global__ void __launch_bounds__(256) k_fin(float* __restrict__ ws,
                                             float* __restrict__ out) {
    const int b = blockIdx.x, t = threadIdx.x;
    float* acc = ws + ACC_OFF;
    unsigned int* cnt = reinterpret_cast<unsigned int*>(ws) + CNT_OFF;

    // elem: min over 8 chunks of 4 cells, then local sum
    const int cell = b * 1024 + t * 4;
    float4 mv = *reinterpret_cast<const float4*>(ws + cell);
    #pragma unroll
    for (int c = 1; c < 8; ++c) {
        float4 v = *reinterpret_cast<const float4*>(ws + c * (M_ * D_) + cell);
        mv.x = fminf(mv.x, v.x); mv.y = fminf(mv.y, v.y);
        mv.z = fminf(mv.z, v.z); mv.w = fminf(mv.w, v.w);
    }
    float s_elem = (mv.x + mv.y) + (mv.z + mv.w);

    // sum path: m in [b*8, b*8+8), 8 lanes per m cover 32 partials
    float s_sum = 0.f;
    if (t < 64) {
        const int m = b * 8 + (t >> 3);
        const int j = t & 7;
        float4 v = *reinterpret_cast<const float4*>(ws + PB_SUM + m * 32 + j * 4);
        float mn = min4(v);
        mn = fminf(mn, __shfl_xor(mn, 1));
        mn = fminf(mn, __shfl_xor(mn, 2));
        mn = fminf(mn, __shfl_xor(mn, 4));
        if ((t & 7) == 0) s_sum = mn;
    }

    #pragma unroll
    for (int off = 32; off; off >>= 1) {
        s_elem += __shfl_xor(s_elem, off);
        s_sum  += __shfl_xor(s_sum, off);
    }
    __shared__ float sm[8];
    const int w = t >> 6;
    if ((t & 63) == 0) { sm[w] = s_elem; sm[4 + w] = s_sum; }
    __syncthreads();
    if (t == 0) {
        float te = sm[0] + sm[1] + sm[2] + sm[3];
        float ts = sm[4] + sm[5] + sm[6] + sm[7];
        atomicAdd(&acc[0], ts);
        atomicAdd(&acc[1], te);
        __threadfence();
        unsigned int old = atomicAdd(cnt, 1u);
        if (old == 63u) {
            float a0 = atomicAdd(&acc[0], 0.f);   // RMW read: coherent
            float a1 = atomicAdd(&acc[1], 0.f);
            out[0] = a0 * (1.0f / 512.0f);
            out[1] = a1 * (1.0f / 65536.0f);
        }
    }
}

extern "C" void kernel_launch(void* const* d_in, const int* in_sizes, int n_in,
                              void* d_out, int out_size, void* d_ws, size_t ws_size,
                              hipStream_t stream) {
    const float* z     = (const float*)d_in[0];
    const float* e     = (const float*)d_in[1];
    const float* probs = (const float*)d_in[2];
    const float* drop  = (const float*)d_in[3];
    float* out = (float*)d_out;
    float* ws  = (float*)d_ws;

    k_part<<<dim3(640), dim3(256), 0, stream>>>(z, e, probs, drop, out, ws);
    k_fin<<<dim3(64), dim3(256), 0, stream>>>(ws, out);
}